// Round 15
// baseline (823.275 us; speedup 1.0000x reference)
//
#include <hip/hip_runtime.h>

typedef unsigned short u16;
typedef short s16x8 __attribute__((ext_vector_type(8)));
typedef float f32x4 __attribute__((ext_vector_type(4)));

constexpr int NNODES = 4000;
constexpr int NEDGES = 50000;
constexpr int NGRID  = 12;
constexpr int HD     = 128;   // H == BD
constexpr int H4     = 512;   // 4*H
constexpr int NLAY   = 2;

// ---- workspace layout (float offsets) ----
constexpr size_t OFF_GN   = 0;          // grid_node: 144000
constexpr size_t OFF_PS   = 144000;     // possum (300) + pad
constexpr size_t OFF_CNT  = 144304;     // cnt (100) + pad
constexpr size_t OFF_FK   = 144512;     // fk: 2*144*128 = 36864
constexpr size_t OFF_X    = 181376;     // x: 6144000
constexpr size_t OFF_X1   = 6325376;    // x1: f32 accum (slow) / bf16 h buffer (fast)
constexpr size_t OFF_WB   = 12469376;   // u16 weight region
constexpr size_t OFF_ROWP = 12625024;   // rowptr: 4001 ints (+pad)
constexpr size_t OFF_DEG  = 12629032;   // deg: 4000 ints
constexpr size_t OFF_CUR  = 12633032;   // cursor: 4000 ints (adjacent to deg: merged memset)
constexpr size_t OFF_ESRT = 12637032;   // esorted: 50000 ints (reused: RO1T after k_einv)
constexpr size_t OFF_EIPB = 12687032;   // eipb: 600048 rows x 16 u16 = 4800384 floats
constexpr size_t OFF_W1T  = 17487416;   // W1T: 128x32 u16 = 2048 floats
constexpr size_t OFF_SRCS = 17489464;   // srcs: 50000 ints
constexpr size_t OFF_END_SLOW = 17539464;  // ~70.2 MiB — proven to fit
// fast path: kern buffers (u16), 600000 rows x 128 each
constexpr size_t OFF_BAS  = 17539464;
constexpr size_t KERN_F   = 38400000;             // floats per kern buffer
constexpr size_t OFF_END_FAST  = OFF_BAS + KERN_F;      // ~223.8 MiB — proven
constexpr size_t OFF_END_DUAL  = OFF_BAS + 2*KERN_F;    // ~377 MiB — proven (r8..r14)

constexpr size_t WB_W2T = 0;        // 128x128  -> [n*128+k]
constexpr size_t WB_WCT = 16384;    // 2 x 128x128
constexpr size_t WB_F1T = 49152;    // 2 x (512n x 128k)
constexpr size_t WB_F2T = 180224;   // 2 x (128n x 512k)

__device__ __forceinline__ u16 f2bf(float f){
  union { float f; unsigned int i; } v; v.f = f;
  unsigned int x = v.i;
  x += 0x7fffu + ((x >> 16) & 1u);   // RNE
  return (u16)(x >> 16);
}
__device__ __forceinline__ float bf2f(u16 u){
  union { unsigned int i; float f; } v; v.i = ((unsigned int)u) << 16; return v.f;
}
// r12/r13 A/B: libm erff beats A&S rcp+exp approx on gfx950 (k_kern 142 vs 159 us).
// r13: dual-layer G3 interleave doubled acc VGPRs (64->96), occupancy 42->21%, k_kern 204us. REVERTED.
__device__ __forceinline__ float gelu_f(float x){
  return 0.5f * x * (1.0f + erff(x * 0.70710678118654752f));
}
__device__ __forceinline__ float waveReduceSum(float v){
  #pragma unroll
  for(int off = 32; off > 0; off >>= 1) v += __shfl_xor(v, off, 64);
  return v;
}
__device__ __forceinline__ f32x4 mfma16(s16x8 a, s16x8 b, f32x4 c){
  return __builtin_amdgcn_mfma_f32_16x16x32_bf16(a, b, c, 0, 0, 0);
}

// ---------------- per-graph stats ----------------
__global__ void k_stats(const float* __restrict__ pos, const int* __restrict__ batch,
                        float* __restrict__ possum, float* __restrict__ pcnt){
  int n = blockIdx.x * 256 + threadIdx.x;
  if(n >= NNODES) return;
  int b = batch[n];
  atomicAdd(&possum[b*3+0], pos[n*3+0]);
  atomicAdd(&possum[b*3+1], pos[n*3+1]);
  atomicAdd(&possum[b*3+2], pos[n*3+2]);
  atomicAdd(&pcnt[b], 1.0f);
}

// ---------------- grid_node[n][k][d] ----------------
__global__ void k_gridnode(const float* __restrict__ g0, const float* __restrict__ R,
                           const int* __restrict__ batch, float* __restrict__ grid_node){
  int idx = blockIdx.x * 256 + threadIdx.x;
  if(idx >= NNODES*NGRID) return;
  int n = idx / NGRID, k = idx % NGRID;
  int b = batch[n];
  float g[3];
  #pragma unroll
  for(int j=0;j<3;j++) g[j] = g0[k*3+j];
  #pragma unroll
  for(int i=0;i<3;i++){
    float s = 0.f;
    #pragma unroll
    for(int j=0;j<3;j++) s += R[b*9+i*3+j] * g[j];
    grid_node[idx*3+i] = s;
  }
}

// ---------------- embed ----------------
__global__ __launch_bounds__(128) void k_embed(
    const float* __restrict__ pos, const float* __restrict__ vel, const float* __restrict__ charges,
    const int* __restrict__ batch, const float* __restrict__ possum, const float* __restrict__ pcnt,
    const float* __restrict__ grid_node, const float* __restrict__ W_embed, float* __restrict__ x)
{
  int n = blockIdx.x; int t = threadIdx.x;
  __shared__ float feats[NGRID][4];
  __shared__ float sgn[NGRID][3];
  if(t < 36) sgn[t/3][t%3] = grid_node[n*36 + t];
  __syncthreads();
  if(t < NGRID){
    int b = batch[n];
    float inv = 1.0f / fmaxf(pcnt[b], 1.0f);
    float v0=vel[n*3], v1=vel[n*3+1], v2=vel[n*3+2];
    float p0=pos[n*3]   - possum[b*3]*inv;
    float p1=pos[n*3+1] - possum[b*3+1]*inv;
    float p2=pos[n*3+2] - possum[b*3+2]*inv;
    float g0=sgn[t][0], g1=sgn[t][1], g2=sgn[t][2];
    feats[t][0] = v0*g0 + v1*g1 + v2*g2;
    feats[t][1] = p0*g0 + p1*g1 + p2*g2;
    feats[t][2] = charges[n];
    feats[t][3] = sqrtf(v0*v0 + v1*v1 + v2*v2);
  }
  __syncthreads();
  float w0=W_embed[0*HD+t], w1=W_embed[1*HD+t];
  float w2=W_embed[2*HD+t], w3=W_embed[3*HD+t];
  #pragma unroll
  for(int k=0;k<NGRID;k++)
    x[(n*NGRID+k)*HD + t] = feats[k][0]*w0 + feats[k][1]*w1 + feats[k][2]*w2 + feats[k][3]*w3;
}

// ---------------- fiber basis -> fk ----------------
__global__ __launch_bounds__(128) void k_fiber(
    const float* __restrict__ g0, const float* __restrict__ Wf1, const float* __restrict__ bfb1,
    const float* __restrict__ Wf2, const float* __restrict__ bfb2, const float* __restrict__ W_fiber,
    float* __restrict__ fk)
{
  int po = blockIdx.x; int p = po / NGRID, o = po % NGRID; int c = threadIdx.x;
  __shared__ float st[HD];
  __shared__ float sfb[HD];
  float fi = 0.f;
  #pragma unroll
  for(int j=0;j<3;j++) fi += g0[p*3+j] * g0[o*3+j];
  float f2 = fi*fi;
  st[c] = gelu_f(fi*Wf1[c] + f2*Wf1[HD+c] + bfb1[c]);
  __syncthreads();
  float a = bfb2[c];
  for(int j=0;j<HD;j++) a += st[j] * Wf2[j*HD+c];
  sfb[c] = gelu_f(a);
  __syncthreads();
  for(int l=0;l<NLAY;l++){
    float s = 0.f;
    for(int j=0;j<HD;j++) s += sfb[j] * W_fiber[l*HD*HD + j*HD + c];
    fk[(l*144 + po)*HD + c] = s;
  }
}

// ---------------- fused weight prep (bf16 + transpose), one launch ----------------
__global__ void k_prep(const float* __restrict__ W_b2, const float* __restrict__ W_b1,
                       const float* __restrict__ W_conv, const float* __restrict__ W_ff1,
                       const float* __restrict__ W_ff2,
                       u16* __restrict__ W2T, u16* __restrict__ W1T, u16* __restrict__ WCT,
                       u16* __restrict__ F1T, u16* __restrict__ F2T){
  int idx = blockIdx.x * 256 + threadIdx.x;
  if(idx < 16384){
    int r = idx >> 7, c = idx & 127;
    W2T[c*128 + r] = f2bf(W_b2[idx]);
    return;
  }
  idx -= 16384;
  if(idx < 4096){
    int c = idx >> 5, f = idx & 31;
    W1T[idx] = (f < 12) ? f2bf(W_b1[f*HD + c]) : (u16)0;
    return;
  }
  idx -= 4096;
  if(idx < 32768){
    int l = idx >> 14, j = idx & 16383;
    int r = j >> 7, c = j & 127;
    WCT[l*16384 + c*128 + r] = f2bf(W_conv[l*16384 + j]);
    return;
  }
  idx -= 32768;
  if(idx < 131072){
    int l = idx >> 16, j = idx & 65535;
    int r = j / 512, c = j % 512;
    F1T[l*65536 + c*128 + r] = f2bf(W_ff1[l*65536 + j]);
    return;
  }
  idx -= 131072;
  if(idx < 131072){
    int l = idx >> 16, j = idx & 65535;
    int r = j / 128, c = j % 128;
    F2T[l*65536 + c*512 + r] = f2bf(W_ff2[l*65536 + j]);
  }
}

// ---------------- readout weight prep (into dead esorted region, after k_einv) ----------------
__global__ void k_prepro(const float* __restrict__ W_ro1, u16* __restrict__ RO1T){
  int idx = blockIdx.x * 256 + threadIdx.x;
  if(idx >= 16384) return;
  int r = idx >> 7, c = idx & 127;
  RO1T[c*128 + r] = f2bf(W_ro1[idx]);
}

// ---------------- CSR build ----------------
__global__ void k_deg(const int* __restrict__ eidx, int* __restrict__ deg){
  int e = blockIdx.x * 256 + threadIdx.x;
  if(e >= NEDGES) return;
  atomicAdd(&deg[eidx[NEDGES + e]], 1);
}

__global__ __launch_bounds__(256) void k_scan(const int* __restrict__ deg, int* __restrict__ rowptr){
  int t = threadIdx.x;
  __shared__ int part[256];
  int base = t * 16;
  int lp[16]; int s = 0;
  #pragma unroll
  for(int i=0;i<16;i++){
    int idx = base + i;
    int v = (idx < NNODES) ? deg[idx] : 0;
    lp[i] = s; s += v;
  }
  part[t] = s;
  __syncthreads();
  for(int off=1; off<256; off<<=1){
    int v2 = (t >= off) ? part[t-off] : 0;
    __syncthreads();
    part[t] += v2;
    __syncthreads();
  }
  int excl = part[t] - s;
  #pragma unroll
  for(int i=0;i<16;i++){
    int idx = base + i;
    if(idx < NNODES) rowptr[idx] = excl + lp[i];
  }
  if(t == 255) rowptr[NNODES] = part[255];
}

__global__ void k_bucket(const int* __restrict__ eidx, const int* __restrict__ rowptr,
                         int* __restrict__ cur, int* __restrict__ esorted, int* __restrict__ srcs){
  int e = blockIdx.x * 256 + threadIdx.x;
  if(e >= NEDGES) return;
  int d = eidx[NEDGES + e];
  int p = atomicAdd(&cur[d], 1);
  int slot = rowptr[d] + p;
  esorted[slot] = e;
  srcs[slot] = eidx[e];
}

// ---------------- edge invariants -> eipb (bf16, MFMA-A layout, 16-wide K) ----------------
__global__ void k_einv(const int* __restrict__ esorted, const int* __restrict__ eidx,
                       const float* __restrict__ pos, const float* __restrict__ charges,
                       const float* __restrict__ grid_node, u16* __restrict__ eipb){
  int row = blockIdx.x * 256 + threadIdx.x;
  if(row >= NEDGES*NGRID) return;
  int p = row / NGRID, kg = row - p*NGRID;
  int e = esorted[p];
  int sr = eidx[e], ds = eidx[NEDGES + e];
  float r0 = pos[sr*3]   - pos[ds*3];
  float r1 = pos[sr*3+1] - pos[ds*3+1];
  float r2 = pos[sr*3+2] - pos[ds*3+2];
  float cp = charges[sr] * charges[ds];
  float g0 = grid_node[sr*36 + kg*3];
  float g1 = grid_node[sr*36 + kg*3 + 1];
  float g2 = grid_node[sr*36 + kg*3 + 2];
  float inv1 = r0*g0 + r1*g1 + r2*g2;
  float d0 = r0 - inv1*g0, d1 = r1 - inv1*g1, d2 = r2 - inv1*g2;
  float inv2 = sqrtf(d0*d0 + d1*d1 + d2*d2);
  float ei[3] = {inv1, inv2, cp};
  s16x8 lo, hi;
  #pragma unroll
  for(int i=0;i<3;i++) lo[i] = (short)f2bf(ei[i]);
  lo[3] = (short)f2bf(ei[0]*ei[0]);
  lo[4] = (short)f2bf(ei[0]*ei[1]);
  lo[5] = (short)f2bf(ei[0]*ei[2]);
  lo[6] = (short)f2bf(ei[1]*ei[0]);
  lo[7] = (short)f2bf(ei[1]*ei[1]);
  hi[0] = (short)f2bf(ei[1]*ei[2]);
  hi[1] = (short)f2bf(ei[2]*ei[0]);
  hi[2] = (short)f2bf(ei[2]*ei[1]);
  hi[3] = (short)f2bf(ei[2]*ei[2]);
  hi[4] = 0; hi[5] = 0; hi[6] = 0; hi[7] = 0;
  *(s16x8*)&eipb[(size_t)row*16]     = lo;
  *(s16x8*)&eipb[(size_t)row*16 + 8] = hi;
}

constexpr int T1S = 136;  // bf16 LDS row stride

// ---------------- kern precompute: kern_l = gelu(gelu(eip@W1)@W2) @ Wc_l ----------------
__global__ __launch_bounds__(256) void k_kern(
    const u16* __restrict__ eipb, const u16* __restrict__ W1T,
    const float* __restrict__ b1, const float* __restrict__ b2,
    const u16* __restrict__ W2T, const u16* __restrict__ WCT,
    u16* __restrict__ kern, int nl, size_t kstride)
{
  int t = threadIdx.x;
  int lane = t & 63, w = t >> 6, quad = lane >> 4, l16 = lane & 15;
  size_t R0 = (size_t)blockIdx.x * 64;
  __shared__ __align__(16) u16 s_buf[64*T1S];

  float b1v[2], b2v[2];
  #pragma unroll
  for(int nt=0;nt<2;nt++){
    b1v[nt] = b1[(2*w+nt)*16 + l16];
    b2v[nt] = b2[(2*w+nt)*16 + l16];
  }
  const s16x8 zvec = {0,0,0,0,0,0,0,0};

  // G1
  {
    f32x4 a1[4][2];
    #pragma unroll
    for(int mt=0;mt<4;mt++)
      #pragma unroll
      for(int nt=0;nt<2;nt++) a1[mt][nt] = (f32x4){0.f,0.f,0.f,0.f};
    s16x8 Af[4];
    #pragma unroll
    for(int mt=0;mt<4;mt++){
      s16x8 v = *(const s16x8*)&eipb[(R0 + mt*16 + l16)*16 + (quad&1)*8];
      if(quad >= 2) v = zvec;
      Af[mt] = v;
    }
    #pragma unroll
    for(int nt=0;nt<2;nt++){
      s16x8 Bf = *(const s16x8*)&W1T[((2*w+nt)*16 + l16)*32 + quad*8];
      #pragma unroll
      for(int mt=0;mt<4;mt++) a1[mt][nt] = mfma16(Af[mt], Bf, a1[mt][nt]);
    }
    #pragma unroll
    for(int mt=0;mt<4;mt++)
      #pragma unroll
      for(int nt=0;nt<2;nt++)
        #pragma unroll
        for(int i=0;i<4;i++)
          s_buf[(mt*16 + quad*4 + i)*T1S + (2*w+nt)*16 + l16] = f2bf(gelu_f(a1[mt][nt][i] + b1v[nt]));
  }
  __syncthreads();
  // G2
  f32x4 a2[4][2];
  #pragma unroll
  for(int mt=0;mt<4;mt++)
    #pragma unroll
    for(int nt=0;nt<2;nt++) a2[mt][nt] = (f32x4){0.f,0.f,0.f,0.f};
  #pragma unroll
  for(int ks=0; ks<4; ks++){
    s16x8 Af[4];
    #pragma unroll
    for(int mt=0;mt<4;mt++)
      Af[mt] = *(const s16x8*)&s_buf[(mt*16 + l16)*T1S + ks*32 + quad*8];
    #pragma unroll
    for(int nt=0;nt<2;nt++){
      s16x8 Bf = *(const s16x8*)&W2T[((2*w+nt)*16 + l16)*HD + ks*32 + quad*8];
      #pragma unroll
      for(int mt=0;mt<4;mt++) a2[mt][nt] = mfma16(Af[mt], Bf, a2[mt][nt]);
    }
  }
  __syncthreads();
  #pragma unroll
  for(int mt=0;mt<4;mt++)
    #pragma unroll
    for(int nt=0;nt<2;nt++)
      #pragma unroll
      for(int i=0;i<4;i++)
        s_buf[(mt*16 + quad*4 + i)*T1S + (2*w+nt)*16 + l16] = f2bf(gelu_f(a2[mt][nt][i] + b2v[nt]));
  __syncthreads();
  // G3 (simple per-layer loop)
  for(int l=0; l<nl; l++){
    f32x4 a3[4][2];
    #pragma unroll
    for(int mt=0;mt<4;mt++)
      #pragma unroll
      for(int nt=0;nt<2;nt++) a3[mt][nt] = (f32x4){0.f,0.f,0.f,0.f};
    #pragma unroll
    for(int ks=0; ks<4; ks++){
      s16x8 Af[4];
      #pragma unroll
      for(int mt=0;mt<4;mt++)
        Af[mt] = *(const s16x8*)&s_buf[(mt*16 + l16)*T1S + ks*32 + quad*8];
      #pragma unroll
      for(int nt=0;nt<2;nt++){
        s16x8 Bf = *(const s16x8*)&WCT[l*16384 + ((2*w+nt)*16 + l16)*HD + ks*32 + quad*8];
        #pragma unroll
        for(int mt=0;mt<4;mt++) a3[mt][nt] = mfma16(Af[mt], Bf, a3[mt][nt]);
      }
    }
    #pragma unroll
    for(int mt=0;mt<4;mt++)
      #pragma unroll
      for(int nt=0;nt<2;nt++)
        #pragma unroll
        for(int i=0;i<4;i++)
          kern[l*kstride + (R0 + mt*16 + quad*4 + i)*HD + (2*w+nt)*16 + l16] = f2bf(a3[mt][nt][i]);
  }
}

// ---------------- gather + fiber mix + LN -> bf16 h, vectorized 2ch/thread, 2 nodes/block ----
// wave w owns a full 128-ch row as 64 pairs -> LN is pure wave reduce, 1 barrier total.
__global__ __launch_bounds__(256) void k_gather(
    const u16* __restrict__ kern, const float* __restrict__ x,
    const int* __restrict__ rowptr, const int* __restrict__ srcs,
    const float* __restrict__ fkl, const float* __restrict__ bconv,
    const float* __restrict__ gamma, const float* __restrict__ beta,
    u16* __restrict__ hout)
{
  int t = threadIdx.x;
  __shared__ float raw[2][NGRID*HD];   // 12 KB
  // gather phase: nd = node-in-pair, g = k-half, c2 = channel pair base
  {
    int nd = t >> 7;
    int tt = t & 127;
    int g  = tt >> 6;
    int c2 = (tt & 63) * 2;
    int n = blockIdx.x * 2 + nd;
    int base = rowptr[n];
    int d = rowptr[n+1] - base;
    float2 acc[6];
    #pragma unroll
    for(int kk=0;kk<6;kk++){ acc[kk].x = 0.f; acc[kk].y = 0.f; }
    int srcn = (d > 0) ? srcs[base] : 0;
    for(int e=0; e<d; e++){
      int nsrc = (e+1 < d) ? srcs[base+e+1] : 0;   // prefetch next src
      const u16*   kp = &kern[((size_t)(base+e)*NGRID + g*6)*HD + c2];
      const float* xp = &x[((size_t)srcn*NGRID + g*6)*HD + c2];
      #pragma unroll
      for(int kk=0;kk<6;kk++){
        unsigned int u = *(const unsigned int*)(kp + kk*HD);
        float2 xv = *(const float2*)(xp + kk*HD);
        acc[kk].x += bf2f((u16)(u & 0xffffu)) * xv.x;
        acc[kk].y += bf2f((u16)(u >> 16))     * xv.y;
      }
      srcn = nsrc;
    }
    #pragma unroll
    for(int kk=0;kk<6;kk++)
      *(float2*)&raw[nd][(g*6+kk)*HD + c2] = acc[kk];
  }
  __syncthreads();
  // mix + LN phase: wave w -> node (w>>1), p-half (w&1); lane owns channel pair
  {
    int w = t >> 6, lane = t & 63;
    int ndw = w >> 1, ph = w & 1;
    int c2 = lane * 2;
    int nn = blockIdx.x * 2 + ndw;
    float2 bc = *(const float2*)&bconv[c2];
    float2 ga = *(const float2*)&gamma[c2];
    float2 be = *(const float2*)&beta[c2];
    #pragma unroll
    for(int kk=0;kk<6;kk++){
      int p = ph*6 + kk;
      float ax = 0.f, ay = 0.f;
      #pragma unroll
      for(int o=0;o<NGRID;o++){
        float2 fv = *(const float2*)&fkl[(p*NGRID+o)*HD + c2];
        float2 rv = *(const float2*)&raw[ndw][o*HD + c2];
        ax += rv.x * fv.x;
        ay += rv.y * fv.y;
      }
      float vx = ax * (1.0f/12.0f) + bc.x;
      float vy = ay * (1.0f/12.0f) + bc.y;
      float mu = waveReduceSum(vx + vy) * (1.0f/128.0f);
      float dx = vx - mu, dy = vy - mu;
      float var = waveReduceSum(dx*dx + dy*dy) * (1.0f/128.0f);
      float inv = 1.0f / sqrtf(var + 1e-5f);
      u16 h0 = f2bf(dx * inv * ga.x + be.x);
      u16 h1 = f2bf(dy * inv * ga.y + be.y);
      unsigned int pu = (unsigned int)h0 | ((unsigned int)h1 << 16);
      *(unsigned int*)&hout[((size_t)nn*NGRID + p)*HD + c2] = pu;
    }
  }
}

// ---------------- FF1 as dense row-GEMM: h4 = gelu(h @ Wff1 + b1), 32 rows/block ----------------
__global__ __launch_bounds__(256) void k_ff1(
    const u16* __restrict__ F1T, const float* __restrict__ bf1,
    const u16* __restrict__ hin, u16* __restrict__ h4)
{
  int t = threadIdx.x;
  size_t r0 = (size_t)blockIdx.x * 32;
  int lane = t & 63, w = t >> 6, quad = lane >> 4, l16 = lane & 15;
  __shared__ __align__(16) u16 sxh[32*T1S];   // 8.7 KB
  for(int i=t; i<32*HD/8; i+=256){
    int r = (i*8) >> 7, cc = (i*8) & 127;
    *(s16x8*)&sxh[r*T1S + cc] = *(const s16x8*)&hin[r0*HD + (size_t)i*8];
  }
  __syncthreads();
  f32x4 acc[2][8];
  #pragma unroll
  for(int mt=0;mt<2;mt++)
    #pragma unroll
    for(int j=0;j<8;j++) acc[mt][j] = (f32x4){0.f,0.f,0.f,0.f};
  #pragma unroll
  for(int ks=0; ks<4; ks++){
    s16x8 Af0 = *(const s16x8*)&sxh[l16*T1S + ks*32 + quad*8];
    s16x8 Af1 = *(const s16x8*)&sxh[(16 + l16)*T1S + ks*32 + quad*8];
    #pragma unroll
    for(int j=0;j<8;j++){
      int nt = w*8 + j;
      s16x8 Bf = *(const s16x8*)&F1T[((size_t)(nt*16 + l16))*HD + ks*32 + quad*8];
      acc[0][j] = mfma16(Af0, Bf, acc[0][j]);
      acc[1][j] = mfma16(Af1, Bf, acc[1][j]);
    }
  }
  #pragma unroll
  for(int j=0;j<8;j++){
    int col = (w*8+j)*16 + l16;
    float bv = bf1[col];
    #pragma unroll
    for(int mt=0;mt<2;mt++)
      #pragma unroll
      for(int i=0;i<4;i++){
        int row = mt*16 + quad*4 + i;
        h4[(r0 + row)*H4 + col] = f2bf(gelu_f(acc[mt][j][i] + bv));
      }
  }
}

// ---------------- FF2 as dense row-GEMM + residual: x += h4 @ Wff2 + b2 ----------------
__global__ __launch_bounds__(256) void k_ff2(
    const u16* __restrict__ F2T, const float* __restrict__ bf2,
    const u16* __restrict__ h4, float* __restrict__ x)
{
  int t = threadIdx.x;
  size_t r0 = (size_t)blockIdx.x * 32;
  int lane = t & 63, w = t >> 6, quad = lane >> 4, l16 = lane & 15;
  f32x4 acc[2][2];
  #pragma unroll
  for(int mt=0;mt<2;mt++)
    #pragma unroll
    for(int j=0;j<2;j++) acc[mt][j] = (f32x4){0.f,0.f,0.f,0.f};
  for(int ks=0; ks<16; ks++){
    s16x8 Af0 = *(const s16x8*)&h4[(r0 + l16)*H4 + ks*32 + quad*8];
    s16x8 Af1 = *(const s16x8*)&h4[(r0 + 16 + l16)*H4 + ks*32 + quad*8];
    #pragma unroll
    for(int j=0;j<2;j++){
      int nt = w*2 + j;
      s16x8 Bf = *(const s16x8*)&F2T[((size_t)(nt*16 + l16))*H4 + ks*32 + quad*8];
      acc[0][j] = mfma16(Af0, Bf, acc[0][j]);
      acc[1][j] = mfma16(Af1, Bf, acc[1][j]);
    }
  }
  #pragma unroll
  for(int j=0;j<2;j++){
    int col = (w*2+j)*16 + l16;
    float bv = bf2[col];
    #pragma unroll
    for(int mt=0;mt<2;mt++)
      #pragma unroll
      for(int i=0;i<4;i++){
        size_t row = r0 + mt*16 + quad*4 + i;
        x[row*HD + col] += acc[mt][j][i] + bv;
      }
  }
}

// ---------------- SLOW fallback conv (round-5 structure, used if ws too small) ----------------
__global__ __launch_bounds__(256) void k_conv_slow(
    const u16* __restrict__ eipb, const u16* __restrict__ W1T,
    const float* __restrict__ b1, const float* __restrict__ b2,
    const u16* __restrict__ W2T, const u16* __restrict__ WCT,
    const float* __restrict__ x,
    const int* __restrict__ rowptr, const int* __restrict__ srcs,
    float* __restrict__ x1o)
{
  int n = blockIdx.x; int t = threadIdx.x;
  int lane = t & 63, w = t >> 6, quad = lane >> 4, l16 = lane & 15;

  __shared__ __align__(16) u16 s_t1h[48*T1S];
  __shared__ __align__(16) u16 s_bas[48*T1S];
  __shared__ __align__(16) float accLDS[NGRID*HD];

  int base = rowptr[n];
  int d = rowptr[n+1] - base;

  float b1v[2], b2v[2];
  #pragma unroll
  for(int nt=0;nt<2;nt++){
    b1v[nt] = b1[(2*w+nt)*16 + l16];
    b2v[nt] = b2[(2*w+nt)*16 + l16];
  }

  for(int i=t; i<NGRID*HD; i+=256) accLDS[i] = 0.f;
  __syncthreads();

  f32x4 accv[3][2];
  #pragma unroll
  for(int mt=0;mt<3;mt++)
    #pragma unroll
    for(int nt=0;nt<2;nt++) accv[mt][nt] = (f32x4){0.f,0.f,0.f,0.f};

  const s16x8 zvec = {0,0,0,0,0,0,0,0};

  for(int ch=0; ch<d; ch+=4){
    size_t rowb = (size_t)(base + ch) * NGRID;
    s16x8 Af1[3];
    #pragma unroll
    for(int mt=0;mt<3;mt++){
      s16x8 v = *(const s16x8*)&eipb[(rowb + mt*16 + l16)*16 + (quad&1)*8];
      if(quad >= 2) v = zvec;
      Af1[mt] = v;
    }
    float xv[3][4][2];
    #pragma unroll
    for(int mt=0;mt<3;mt++)
      #pragma unroll
      for(int i=0;i<4;i++){
        int row = mt*16 + quad*4 + i;
        int e = row / 12;
        int k = row - e*12;
        int ei2 = base + ch + e;
        int srcn = srcs[min(ei2, NEDGES-1)];
        float m = (ch + e < d) ? 1.0f : 0.0f;
        const float* xp = &x[((size_t)srcn*NGRID + k)*HD + l16];
        #pragma unroll
        for(int nt=0;nt<2;nt++)
          xv[mt][i][nt] = xp[(2*w+nt)*16] * m;
      }
    {
      f32x4 a1[3][2];
      #pragma unroll
      for(int mt=0;mt<3;mt++)
        #pragma unroll
        for(int nt=0;nt<2;nt++) a1[mt][nt] = (f32x4){0.f,0.f,0.f,0.f};
      #pragma unroll
      for(int nt=0;nt<2;nt++){
        s16x8 Bf = *(const s16x8*)&W1T[((2*w+nt)*16 + l16)*32 + quad*8];
        #pragma unroll
        for(int mt=0;mt<3;mt++) a1[mt][nt] = mfma16(Af1[mt], Bf, a1[mt][nt]);
      }
      #pragma unroll
      for(int mt=0;mt<3;mt++)
        #pragma unroll
        for(int nt=0;nt<2;nt++)
          #pragma unroll
          for(int i=0;i<4;i++)
            s_t1h[(mt*16 + quad*4 + i)*T1S + (2*w+nt)*16 + l16] = f2bf(gelu_f(a1[mt][nt][i] + b1v[nt]));
    }
    __syncthreads();
    {
      f32x4 a2[3][2];
      #pragma unroll
      for(int mt=0;mt<3;mt++)
        #pragma unroll
        for(int nt=0;nt<2;nt++) a2[mt][nt] = (f32x4){0.f,0.f,0.f,0.f};
      #pragma unroll
      for(int ks=0; ks<4; ks++){
        s16x8 Af[3];
        #pragma unroll
        for(int mt=0;mt<3;mt++)
          Af[mt] = *(const s16x8*)&s_t1h[(mt*16 + l16)*T1S + ks*32 + quad*8];
        #pragma unroll
        for(int nt=0;nt<2;nt++){
          s16x8 Bf = *(const s16x8*)&W2T[((2*w+nt)*16 + l16)*HD + ks*32 + quad*8];
          #pragma unroll
          for(int mt=0;mt<3;mt++) a2[mt][nt] = mfma16(Af[mt], Bf, a2[mt][nt]);
        }
      }
      #pragma unroll
      for(int mt=0;mt<3;mt++)
        #pragma unroll
        for(int nt=0;nt<2;nt++)
          #pragma unroll
          for(int i=0;i<4;i++)
            s_bas[(mt*16 + quad*4 + i)*T1S + (2*w+nt)*16 + l16] = f2bf(gelu_f(a2[mt][nt][i] + b2v[nt]));
    }
    __syncthreads();
    {
      f32x4 a3[3][2];
      #pragma unroll
      for(int mt=0;mt<3;mt++)
        #pragma unroll
        for(int nt=0;nt<2;nt++) a3[mt][nt] = (f32x4){0.f,0.f,0.f,0.f};
      #pragma unroll
      for(int ks=0; ks<4; ks++){
        s16x8 Af[3];
        #pragma unroll
        for(int mt=0;mt<3;mt++)
          Af[mt] = *(const s16x8*)&s_bas[(mt*16 + l16)*T1S + ks*32 + quad*8];
        #pragma unroll
        for(int nt=0;nt<2;nt++){
          s16x8 Bf = *(const s16x8*)&WCT[((2*w+nt)*16 + l16)*HD + ks*32 + quad*8];
          #pragma unroll
          for(int mt=0;mt<3;mt++) a3[mt][nt] = mfma16(Af[mt], Bf, a3[mt][nt]);
        }
      }
      #pragma unroll
      for(int mt=0;mt<3;mt++)
        #pragma unroll
        for(int nt=0;nt<2;nt++)
          #pragma unroll
          for(int i=0;i<4;i++)
            accv[mt][nt][i] += a3[mt][nt][i] * xv[mt][i][nt];
    }
  }
  __syncthreads();
  #pragma unroll
  for(int mt=0;mt<3;mt++)
    #pragma unroll
    for(int nt=0;nt<2;nt++)
      #pragma unroll
      for(int i=0;i<4;i++){
        int row = mt*16 + quad*4 + i;
        int k = row % 12;
        atomicAdd(&accLDS[k*HD + (2*w+nt)*16 + l16], accv[mt][nt][i]);
      }
  __syncthreads();
  for(int i=t; i<NGRID*HD; i+=256)
    x1o[(size_t)n*NGRID*HD + i] = accLDS[i];
}

// ---------------- slow-path fused mix + LN + FF + residual (per node) ----------------
constexpr int STS = 520;
__global__ __launch_bounds__(256) void k_ffln(
    const u16* __restrict__ F1T, const float* __restrict__ bf1,
    const u16* __restrict__ F2T, const float* __restrict__ bf2,
    const float* __restrict__ x1raw,
    const float* __restrict__ fkl, const float* __restrict__ bconv,
    const float* __restrict__ gamma, const float* __restrict__ beta,
    float* __restrict__ x)
{
  int n = blockIdx.x; int t = threadIdx.x;
  int lane = t & 63, w = t >> 6, quad = lane >> 4, l16 = lane & 15;
  __shared__ __align__(16) float raw[NGRID*HD];
  __shared__ __align__(16) u16 sxh[16*T1S];
  __shared__ __align__(16) u16 st[16*STS];

  for(int i=t; i<NGRID*HD; i+=256) raw[i] = x1raw[(size_t)n*NGRID*HD + i];
  for(int i=t; i<4*T1S; i+=256) sxh[12*T1S + i] = 0;
  __syncthreads();

  {
    int c0 = lane, c1 = lane + 64;
    float bc0 = bconv[c0], bc1 = bconv[c1];
    float ga0 = gamma[c0], ga1 = gamma[c1];
    float be0 = beta[c0],  be1 = beta[c1];
    #pragma unroll
    for(int pp=0; pp<3; pp++){
      int p = w + pp*4;
      float a0 = 0.f, a1 = 0.f;
      #pragma unroll
      for(int o=0;o<NGRID;o++){
        a0 += raw[o*HD + c0] * fkl[(p*NGRID+o)*HD + c0];
        a1 += raw[o*HD + c1] * fkl[(p*NGRID+o)*HD + c1];
      }
      float v0 = a0 * (1.0f/12.0f) + bc0;
      float v1 = a1 * (1.0f/12.0f) + bc1;
      float mu = waveReduceSum(v0 + v1) * (1.0f/128.0f);
      float d0 = v0 - mu, d1 = v1 - mu;
      float var = waveReduceSum(d0*d0 + d1*d1) * (1.0f/128.0f);
      float inv = 1.0f / sqrtf(var + 1e-5f);
      sxh[p*T1S + c0] = f2bf(d0 * inv * ga0 + be0);
      sxh[p*T1S + c1] = f2bf(d1 * inv * ga1 + be1);
    }
  }
  __syncthreads();
  {
    f32x4 acc1[8];
    #pragma unroll
    for(int j=0;j<8;j++) acc1[j] = (f32x4){0.f,0.f,0.f,0.f};
    #pragma unroll
    for(int ks=0; ks<4; ks++){
      s16x8 Af = *(const s16x8*)&sxh[l16*T1S + ks*32 + quad*8];
      #pragma unroll
      for(int j=0;j<8;j++){
        int nt = w*8 + j;
        s16x8 Bf = *(const s16x8*)&F1T[((size_t)(nt*16 + l16))*HD + ks*32 + quad*8];
        acc1[j] = mfma16(Af, Bf, acc1[j]);
      }
    }
    #pragma unroll
    for(int j=0;j<8;j++){
      int col = (w*8+j)*16 + l16;
      float bv = bf1[col];
      #pragma unroll
      for(int i=0;i<4;i++){
        int row = quad*4 + i;
        st[row*STS + col] = f2bf(gelu_f(acc1[j][i] + bv));
      }
    }
  }
  __syncthreads();
  {
    f32x4 acc2[2];
    #pragma unroll
    for(int j=0;j<2;j++) acc2[j] = (f32x4){0.f,0.f,0.f,0.f};
    for(int ks=0; ks<16; ks++){
      s16x8 Af = *(const s16x8*)&st[l16*STS + ks*32 + quad*8];
      #pragma unroll
      for(int j=0;j<2;j++){
        int nt = w*2 + j;
        s16x8 Bf = *(const s16x8*)&F2T[((size_t)(nt*16 + l16))*H4 + ks*32 + quad*8];
        acc2[j] = mfma16(Af, Bf, acc2[j]);
      }
    }
    #pragma unroll
    for(int j=0;j<2;j++){
      int col = (w*2+j)*16 + l16;
      float bv = bf2[col];
      #pragma unroll
      for(int i=0;i<4;i++){
        int row = quad*4 + i;
        if(row < NGRID){
          size_t idx = ((size_t)n*NGRID + row)*HD + col;
          x[idx] += acc2[j][i] + bv;
        }
      }
    }
  }
}

// ---------------- readout (MFMA, 2 nodes/block) ----------------
__global__ __launch_bounds__(256) void k_readout(
    const float* __restrict__ x, const float* __restrict__ grid_node,
    const u16* __restrict__ RO1T, const float* __restrict__ br1,
    const float* __restrict__ Wr2, const float* __restrict__ br2,
    float* __restrict__ out)
{
  int t = threadIdx.x;
  int n0 = blockIdx.x * 2;
  int lane = t & 63, w = t >> 6, quad = lane >> 4, l16 = lane & 15;
  __shared__ __align__(16) u16 sxh[32*T1S];
  __shared__ float sy[32];
  if(t < 32) sy[t] = 0.f;
  for(int i=t; i<2*NGRID*HD; i+=256){
    int nd = i / (NGRID*HD), rem = i - nd*NGRID*HD;
    int r = rem >> 7, c = rem & 127;
    sxh[(nd*16 + r)*T1S + c] = f2bf(x[(size_t)n0*NGRID*HD + i]);
  }
  for(int i=t; i<4*T1S; i+=256){ sxh[12*T1S + i] = 0; sxh[28*T1S + i] = 0; }
  __syncthreads();
  f32x4 acc[2][2];
  #pragma unroll
  for(int mt=0;mt<2;mt++)
    #pragma unroll
    for(int j=0;j<2;j++) acc[mt][j] = (f32x4){0.f,0.f,0.f,0.f};
  #pragma unroll
  for(int ks=0; ks<4; ks++){
    s16x8 Af0 = *(const s16x8*)&sxh[l16*T1S + ks*32 + quad*8];
    s16x8 Af1 = *(const s16x8*)&sxh[(16 + l16)*T1S + ks*32 + quad*8];
    #pragma unroll
    for(int j=0;j<2;j++){
      int nt = w*2 + j;
      s16x8 Bf = *(const s16x8*)&RO1T[((size_t)(nt*16 + l16))*HD + ks*32 + quad*8];
      acc[0][j] = mfma16(Af0, Bf, acc[0][j]);
      acc[1][j] = mfma16(Af1, Bf, acc[1][j]);
    }
  }
  #pragma unroll
  for(int j=0;j<2;j++){
    int col = (w*2+j)*16 + l16;
    float bv = br1[col];
    float w2v = Wr2[col];
    #pragma unroll
    for(int mt=0;mt<2;mt++)
      #pragma unroll
      for(int i=0;i<4;i++){
        int row = quad*4 + i;
        if(row < NGRID)
          atomicAdd(&sy[mt*16 + row], gelu_f(acc[mt][j][i] + bv) * w2v);
      }
  }
  __syncthreads();
  if(t < 6){
    int nd = t / 3, d = t - nd*3;
    float b2v = br2[0];
    float s = 0.f;
    #pragma unroll
    for(int k=0;k<NGRID;k++)
      s += grid_node[((size_t)(n0+nd)*NGRID + k)*3 + d] * (sy[nd*16 + k] + b2v);
    out[(n0+nd)*3 + d] = s * (1.0f/12.0f);
  }
}

extern "C" void kernel_launch(void* const* d_in, const int* in_sizes, int n_in,
                              void* d_out, int out_size, void* d_ws, size_t ws_size,
                              hipStream_t stream)
{
  const float* pos      = (const float*)d_in[0];
  const float* vel      = (const float*)d_in[1];
  const float* charges  = (const float*)d_in[2];
  const int*   batch    = (const int*)d_in[3];
  const int*   eidx     = (const int*)d_in[4];
  const float* grid0    = (const float*)d_in[5];
  const float* R        = (const float*)d_in[6];
  const float* W_b1     = (const float*)d_in[7];
  const float* b_b1     = (const float*)d_in[8];
  const float* W_b2     = (const float*)d_in[9];
  const float* b_b2     = (const float*)d_in[10];
  const float* W_fb1    = (const float*)d_in[11];
  const float* b_fb1    = (const float*)d_in[12];
  const float* W_fb2    = (const float*)d_in[13];
  const float* b_fb2    = (const float*)d_in[14];
  const float* W_embed  = (const float*)d_in[15];
  const float* W_conv   = (const float*)d_in[16];
  const float* W_fiber  = (const float*)d_in[17];
  const float* b_conv   = (const float*)d_in[18];
  const float* ln_g     = (const float*)d_in[19];
  const float* ln_b     = (const float*)d_in[20];
  const float* W_ff1    = (const float*)d_in[21];
  const float* b_ff1    = (const float*)d_in[22];
  const float* W_ff2    = (const float*)d_in[23];
  const float* b_ff2    = (const float*)d_in[24];
  const float* W_ro1    = (const float*)d_in[25];
  const float* b_ro1    = (const float*)d_in[26];
  const float* W_ro2    = (const float*)d_in[27];
  const float* b_ro2    = (const float*)d_in[28];

  float* ws        = (float*)d_ws;
  float* grid_node = ws + OFF_GN;
  float* possum    = ws + OFF_PS;
  float* pcnt      = ws + OFF_CNT;
  float* fk        = ws + OFF_FK;
  float* x         = ws + OFF_X;
  float* x1        = ws + OFF_X1;
  u16*   WB        = (u16*)(ws + OFF_WB);
  u16*   W2T       = WB + WB_W2T;
  u16*   WCT       = WB + WB_WCT;
  u16*   F1T       = WB + WB_F1T;
  u16*   F2T       = WB + WB_F2T;
  int*   rowptr    = (int*)(ws + OFF_ROWP);
  int*   deg       = (int*)(ws + OFF_DEG);
  int*   cur       = (int*)(ws + OFF_CUR);
  int*   esorted   = (int*)(ws + OFF_ESRT);
  u16*   eipb      = (u16*)(ws + OFF_EIPB);
  u16*   W1T       = (u16*)(ws + OFF_W1T);
  int*   srcs      = (int*)(ws + OFF_SRCS);
  u16*   kern1     = (u16*)(ws + OFF_BAS);
  u16*   RO1T      = (u16*)(ws + OFF_ESRT);   // reuses esorted after k_einv
  u16*   hbuf      = (u16*)x1;                // fast path: bf16 h buffer in x1 region
  const size_t KSTR = (size_t)600000 * HD;

  const bool fast = (ws_size >= OFF_END_FAST * sizeof(float));
  const bool dual = (ws_size >= OFF_END_DUAL * sizeof(float));

  hipMemsetAsync(possum, 0, 512*sizeof(float), stream);
  hipMemsetAsync(deg, 0, 2*NNODES*sizeof(int), stream);   // deg + cur are adjacent
  hipMemsetAsync(eipb + (size_t)NEDGES*NGRID*16, 0, 48*16*sizeof(u16), stream);

  k_stats<<<(NNODES+255)/256, 256, 0, stream>>>(pos, batch, possum, pcnt);
  k_gridnode<<<(NNODES*NGRID+255)/256, 256, 0, stream>>>(grid0, R, batch, grid_node);
  k_embed<<<NNODES, 128, 0, stream>>>(pos, vel, charges, batch, possum, pcnt, grid_node, W_embed, x);
  k_fiber<<<144, 128, 0, stream>>>(grid0, W_fb1, b_fb1, W_fb2, b_fb2, W_fiber, fk);

  k_prep<<<(315392+255)/256, 256, 0, stream>>>(W_b2, W_b1, W_conv, W_ff1, W_ff2,
                                               W2T, W1T, WCT, F1T, F2T);

  k_deg<<<(NEDGES+255)/256, 256, 0, stream>>>(eidx, deg);
  k_scan<<<1, 256, 0, stream>>>(deg, rowptr);
  k_bucket<<<(NEDGES+255)/256, 256, 0, stream>>>(eidx, rowptr, cur, esorted, srcs);

  k_einv<<<(NEDGES*NGRID+255)/256, 256, 0, stream>>>(esorted, eidx, pos, charges, grid_node, eipb);
  // esorted now dead -> RO1T prep into its region
  k_prepro<<<64, 256, 0, stream>>>(W_ro1, RO1T);

  if(fast){
    if(dual)
      k_kern<<<9375, 256, 0, stream>>>(eipb, W1T, b_b1, b_b2, W2T, WCT, kern1, 2, KSTR);
    for(int l=0; l<NLAY; l++){
      if(!dual)
        k_kern<<<9375, 256, 0, stream>>>(eipb, W1T, b_b1, b_b2, W2T, WCT + (size_t)l*16384,
                                         kern1, 1, 0);
      const u16* kl = dual ? (kern1 + (size_t)l*KSTR) : kern1;
      // h4 scratch aliases the CURRENT layer's kern buffer (dead after its gather)
      u16* h4 = dual ? (kern1 + (size_t)l*KSTR) : kern1;
      k_gather<<<NNODES/2, 256, 0, stream>>>(kl, x, rowptr, srcs,
          fk + (size_t)l*144*HD, b_conv + l*HD, ln_g + l*HD, ln_b + l*HD, hbuf);
      k_ff1<<<NNODES*NGRID/32, 256, 0, stream>>>(F1T + (size_t)l*65536, b_ff1 + l*H4, hbuf, h4);
      k_ff2<<<NNODES*NGRID/32, 256, 0, stream>>>(F2T + (size_t)l*65536, b_ff2 + l*HD, h4, x);
    }
  } else {
    for(int l=0; l<NLAY; l++){
      k_conv_slow<<<NNODES, 256, 0, stream>>>(eipb, W1T, b_b1, b_b2, W2T, WCT + (size_t)l*16384,
          x, rowptr, srcs, x1);
      k_ffln<<<NNODES, 256, 0, stream>>>(F1T + (size_t)l*65536, b_ff1 + l*H4,
          F2T + (size_t)l*65536, b_ff2 + l*HD, x1,
          fk + (size_t)l*144*HD, b_conv + l*HD, ln_g + l*HD, ln_b + l*HD, x);
    }
  }

  k_readout<<<NNODES/2, 256, 0, stream>>>(x, grid_node, RO1T, b_ro1, W_ro2, b_ro2, (float*)d_out);
}

// Round 16
// 796.695 us; speedup vs baseline: 1.0334x; 1.0334x over previous
//
#include <hip/hip_runtime.h>

typedef unsigned short u16;
typedef short s16x8 __attribute__((ext_vector_type(8)));
typedef float f32x4 __attribute__((ext_vector_type(4)));

constexpr int NNODES = 4000;
constexpr int NEDGES = 50000;
constexpr int NGRID  = 12;
constexpr int HD     = 128;   // H == BD
constexpr int H4     = 512;   // 4*H
constexpr int NLAY   = 2;

// ---- workspace layout (float offsets) ----
constexpr size_t OFF_GN   = 0;          // grid_node: 144000
constexpr size_t OFF_PS   = 144000;     // possum (300) + pad
constexpr size_t OFF_CNT  = 144304;     // cnt (100) + pad
constexpr size_t OFF_FK   = 144512;     // fk: 2*144*128 = 36864
constexpr size_t OFF_X    = 181376;     // x: 6144000
constexpr size_t OFF_X1   = 6325376;    // x1: f32 accum (slow) / bf16 h buffer (fast)
constexpr size_t OFF_WB   = 12469376;   // u16 weight region
constexpr size_t OFF_ROWP = 12625024;   // rowptr: 4001 ints (+pad)
constexpr size_t OFF_DEG  = 12629032;   // deg: 4000 ints
constexpr size_t OFF_CUR  = 12633032;   // cursor: 4000 ints
constexpr size_t OFF_ESRT = 12637032;   // esorted: 50000 ints (reused: RO1T after k_einv)
constexpr size_t OFF_EIPB = 12687032;   // eipb: 600048 rows x 16 u16 = 4800384 floats
constexpr size_t OFF_W1T  = 17487416;   // W1T: 128x32 u16 = 2048 floats
constexpr size_t OFF_SRCS = 17489464;   // srcs: 50000 ints
constexpr size_t OFF_END_SLOW = 17539464;  // ~70.2 MiB — proven to fit
// fast path: kern buffers (u16), 600000 rows x 128 each
constexpr size_t OFF_BAS  = 17539464;
constexpr size_t KERN_F   = 38400000;             // floats per kern buffer
constexpr size_t OFF_END_FAST  = OFF_BAS + KERN_F;      // ~223.8 MiB — proven
constexpr size_t OFF_END_DUAL  = OFF_BAS + 2*KERN_F;    // ~377 MiB — proven (r8..r15)

constexpr size_t WB_W2T = 0;        // 128x128  -> [n*128+k]
constexpr size_t WB_WCT = 16384;    // 2 x 128x128
constexpr size_t WB_F1T = 49152;    // 2 x (512n x 128k)
constexpr size_t WB_F2T = 180224;   // 2 x (128n x 512k)

__device__ __forceinline__ u16 f2bf(float f){
  union { float f; unsigned int i; } v; v.f = f;
  unsigned int x = v.i;
  x += 0x7fffu + ((x >> 16) & 1u);   // RNE
  return (u16)(x >> 16);
}
__device__ __forceinline__ float bf2f(u16 u){
  union { unsigned int i; float f; } v; v.i = ((unsigned int)u) << 16; return v.f;
}
// Session lessons encoded here:
// r12/r13: libm erff beats A&S rcp+exp approx on gfx950 (k_kern 142 vs 159 us). Keep erff.
// r13: dual-layer G3 interleave doubled acc VGPRs (64->96), occupancy 42->21%: REVERTED.
// r15: gather 2-node/block vectorization was neutral-negative (block parallelism > per-thread width).
__device__ __forceinline__ float gelu_f(float x){
  return 0.5f * x * (1.0f + erff(x * 0.70710678118654752f));
}
__device__ __forceinline__ float waveReduceSum(float v){
  #pragma unroll
  for(int off = 32; off > 0; off >>= 1) v += __shfl_xor(v, off, 64);
  return v;
}
__device__ __forceinline__ f32x4 mfma16(s16x8 a, s16x8 b, f32x4 c){
  return __builtin_amdgcn_mfma_f32_16x16x32_bf16(a, b, c, 0, 0, 0);
}

// ---------------- per-graph stats ----------------
__global__ void k_stats(const float* __restrict__ pos, const int* __restrict__ batch,
                        float* __restrict__ possum, float* __restrict__ pcnt){
  int n = blockIdx.x * 256 + threadIdx.x;
  if(n >= NNODES) return;
  int b = batch[n];
  atomicAdd(&possum[b*3+0], pos[n*3+0]);
  atomicAdd(&possum[b*3+1], pos[n*3+1]);
  atomicAdd(&possum[b*3+2], pos[n*3+2]);
  atomicAdd(&pcnt[b], 1.0f);
}

// ---------------- grid_node[n][k][d] ----------------
__global__ void k_gridnode(const float* __restrict__ g0, const float* __restrict__ R,
                           const int* __restrict__ batch, float* __restrict__ grid_node){
  int idx = blockIdx.x * 256 + threadIdx.x;
  if(idx >= NNODES*NGRID) return;
  int n = idx / NGRID, k = idx % NGRID;
  int b = batch[n];
  float g[3];
  #pragma unroll
  for(int j=0;j<3;j++) g[j] = g0[k*3+j];
  #pragma unroll
  for(int i=0;i<3;i++){
    float s = 0.f;
    #pragma unroll
    for(int j=0;j<3;j++) s += R[b*9+i*3+j] * g[j];
    grid_node[idx*3+i] = s;
  }
}

// ---------------- embed ----------------
__global__ __launch_bounds__(128) void k_embed(
    const float* __restrict__ pos, const float* __restrict__ vel, const float* __restrict__ charges,
    const int* __restrict__ batch, const float* __restrict__ possum, const float* __restrict__ pcnt,
    const float* __restrict__ grid_node, const float* __restrict__ W_embed, float* __restrict__ x)
{
  int n = blockIdx.x; int t = threadIdx.x;
  __shared__ float feats[NGRID][4];
  __shared__ float sgn[NGRID][3];
  if(t < 36) sgn[t/3][t%3] = grid_node[n*36 + t];
  __syncthreads();
  if(t < NGRID){
    int b = batch[n];
    float inv = 1.0f / fmaxf(pcnt[b], 1.0f);
    float v0=vel[n*3], v1=vel[n*3+1], v2=vel[n*3+2];
    float p0=pos[n*3]   - possum[b*3]*inv;
    float p1=pos[n*3+1] - possum[b*3+1]*inv;
    float p2=pos[n*3+2] - possum[b*3+2]*inv;
    float g0=sgn[t][0], g1=sgn[t][1], g2=sgn[t][2];
    feats[t][0] = v0*g0 + v1*g1 + v2*g2;
    feats[t][1] = p0*g0 + p1*g1 + p2*g2;
    feats[t][2] = charges[n];
    feats[t][3] = sqrtf(v0*v0 + v1*v1 + v2*v2);
  }
  __syncthreads();
  float w0=W_embed[0*HD+t], w1=W_embed[1*HD+t];
  float w2=W_embed[2*HD+t], w3=W_embed[3*HD+t];
  #pragma unroll
  for(int k=0;k<NGRID;k++)
    x[(n*NGRID+k)*HD + t] = feats[k][0]*w0 + feats[k][1]*w1 + feats[k][2]*w2 + feats[k][3]*w3;
}

// ---------------- fiber basis -> fk ----------------
__global__ __launch_bounds__(128) void k_fiber(
    const float* __restrict__ g0, const float* __restrict__ Wf1, const float* __restrict__ bfb1,
    const float* __restrict__ Wf2, const float* __restrict__ bfb2, const float* __restrict__ W_fiber,
    float* __restrict__ fk)
{
  int po = blockIdx.x; int p = po / NGRID, o = po % NGRID; int c = threadIdx.x;
  __shared__ float st[HD];
  __shared__ float sfb[HD];
  float fi = 0.f;
  #pragma unroll
  for(int j=0;j<3;j++) fi += g0[p*3+j] * g0[o*3+j];
  float f2 = fi*fi;
  st[c] = gelu_f(fi*Wf1[c] + f2*Wf1[HD+c] + bfb1[c]);
  __syncthreads();
  float a = bfb2[c];
  for(int j=0;j<HD;j++) a += st[j] * Wf2[j*HD+c];
  sfb[c] = gelu_f(a);
  __syncthreads();
  for(int l=0;l<NLAY;l++){
    float s = 0.f;
    for(int j=0;j<HD;j++) s += sfb[j] * W_fiber[l*HD*HD + j*HD + c];
    fk[(l*144 + po)*HD + c] = s;
  }
}

// ---------------- fused weight prep (bf16 + transpose), one launch ----------------
__global__ void k_prep(const float* __restrict__ W_b2, const float* __restrict__ W_b1,
                       const float* __restrict__ W_conv, const float* __restrict__ W_ff1,
                       const float* __restrict__ W_ff2,
                       u16* __restrict__ W2T, u16* __restrict__ W1T, u16* __restrict__ WCT,
                       u16* __restrict__ F1T, u16* __restrict__ F2T){
  int idx = blockIdx.x * 256 + threadIdx.x;
  if(idx < 16384){
    int r = idx >> 7, c = idx & 127;
    W2T[c*128 + r] = f2bf(W_b2[idx]);
    return;
  }
  idx -= 16384;
  if(idx < 4096){
    int c = idx >> 5, f = idx & 31;
    W1T[idx] = (f < 12) ? f2bf(W_b1[f*HD + c]) : (u16)0;
    return;
  }
  idx -= 4096;
  if(idx < 32768){
    int l = idx >> 14, j = idx & 16383;
    int r = j >> 7, c = j & 127;
    WCT[l*16384 + c*128 + r] = f2bf(W_conv[l*16384 + j]);
    return;
  }
  idx -= 32768;
  if(idx < 131072){
    int l = idx >> 16, j = idx & 65535;
    int r = j / 512, c = j % 512;
    F1T[l*65536 + c*128 + r] = f2bf(W_ff1[l*65536 + j]);
    return;
  }
  idx -= 131072;
  if(idx < 131072){
    int l = idx >> 16, j = idx & 65535;
    int r = j / 128, c = j % 128;
    F2T[l*65536 + c*512 + r] = f2bf(W_ff2[l*65536 + j]);
  }
}

// ---------------- readout weight prep (into dead esorted region, after k_einv) ----------------
__global__ void k_prepro(const float* __restrict__ W_ro1, u16* __restrict__ RO1T){
  int idx = blockIdx.x * 256 + threadIdx.x;
  if(idx >= 16384) return;
  int r = idx >> 7, c = idx & 127;
  RO1T[c*128 + r] = f2bf(W_ro1[idx]);
}

// ---------------- CSR build ----------------
__global__ void k_deg(const int* __restrict__ eidx, int* __restrict__ deg){
  int e = blockIdx.x * 256 + threadIdx.x;
  if(e >= NEDGES) return;
  atomicAdd(&deg[eidx[NEDGES + e]], 1);
}

__global__ __launch_bounds__(256) void k_scan(const int* __restrict__ deg, int* __restrict__ rowptr){
  int t = threadIdx.x;
  __shared__ int part[256];
  int base = t * 16;
  int lp[16]; int s = 0;
  #pragma unroll
  for(int i=0;i<16;i++){
    int idx = base + i;
    int v = (idx < NNODES) ? deg[idx] : 0;
    lp[i] = s; s += v;
  }
  part[t] = s;
  __syncthreads();
  for(int off=1; off<256; off<<=1){
    int v2 = (t >= off) ? part[t-off] : 0;
    __syncthreads();
    part[t] += v2;
    __syncthreads();
  }
  int excl = part[t] - s;
  #pragma unroll
  for(int i=0;i<16;i++){
    int idx = base + i;
    if(idx < NNODES) rowptr[idx] = excl + lp[i];
  }
  if(t == 255) rowptr[NNODES] = part[255];
}

__global__ void k_bucket(const int* __restrict__ eidx, const int* __restrict__ rowptr,
                         int* __restrict__ cur, int* __restrict__ esorted, int* __restrict__ srcs){
  int e = blockIdx.x * 256 + threadIdx.x;
  if(e >= NEDGES) return;
  int d = eidx[NEDGES + e];
  int p = atomicAdd(&cur[d], 1);
  int slot = rowptr[d] + p;
  esorted[slot] = e;
  srcs[slot] = eidx[e];
}

// ---------------- edge invariants -> eipb (bf16, MFMA-A layout, 16-wide K) ----------------
__global__ void k_einv(const int* __restrict__ esorted, const int* __restrict__ eidx,
                       const float* __restrict__ pos, const float* __restrict__ charges,
                       const float* __restrict__ grid_node, u16* __restrict__ eipb){
  int row = blockIdx.x * 256 + threadIdx.x;
  if(row >= NEDGES*NGRID) return;
  int p = row / NGRID, kg = row - p*NGRID;
  int e = esorted[p];
  int sr = eidx[e], ds = eidx[NEDGES + e];
  float r0 = pos[sr*3]   - pos[ds*3];
  float r1 = pos[sr*3+1] - pos[ds*3+1];
  float r2 = pos[sr*3+2] - pos[ds*3+2];
  float cp = charges[sr] * charges[ds];
  float g0 = grid_node[sr*36 + kg*3];
  float g1 = grid_node[sr*36 + kg*3 + 1];
  float g2 = grid_node[sr*36 + kg*3 + 2];
  float inv1 = r0*g0 + r1*g1 + r2*g2;
  float d0 = r0 - inv1*g0, d1 = r1 - inv1*g1, d2 = r2 - inv1*g2;
  float inv2 = sqrtf(d0*d0 + d1*d1 + d2*d2);
  float ei[3] = {inv1, inv2, cp};
  s16x8 lo, hi;
  #pragma unroll
  for(int i=0;i<3;i++) lo[i] = (short)f2bf(ei[i]);
  lo[3] = (short)f2bf(ei[0]*ei[0]);
  lo[4] = (short)f2bf(ei[0]*ei[1]);
  lo[5] = (short)f2bf(ei[0]*ei[2]);
  lo[6] = (short)f2bf(ei[1]*ei[0]);
  lo[7] = (short)f2bf(ei[1]*ei[1]);
  hi[0] = (short)f2bf(ei[1]*ei[2]);
  hi[1] = (short)f2bf(ei[2]*ei[0]);
  hi[2] = (short)f2bf(ei[2]*ei[1]);
  hi[3] = (short)f2bf(ei[2]*ei[2]);
  hi[4] = 0; hi[5] = 0; hi[6] = 0; hi[7] = 0;
  *(s16x8*)&eipb[(size_t)row*16]     = lo;
  *(s16x8*)&eipb[(size_t)row*16 + 8] = hi;
}

constexpr int T1S = 136;  // bf16 LDS row stride

// ---------------- kern precompute: kern_l = gelu(gelu(eip@W1)@W2) @ Wc_l ----------------
__global__ __launch_bounds__(256) void k_kern(
    const u16* __restrict__ eipb, const u16* __restrict__ W1T,
    const float* __restrict__ b1, const float* __restrict__ b2,
    const u16* __restrict__ W2T, const u16* __restrict__ WCT,
    u16* __restrict__ kern, int nl, size_t kstride)
{
  int t = threadIdx.x;
  int lane = t & 63, w = t >> 6, quad = lane >> 4, l16 = lane & 15;
  size_t R0 = (size_t)blockIdx.x * 64;
  __shared__ __align__(16) u16 s_buf[64*T1S];

  float b1v[2], b2v[2];
  #pragma unroll
  for(int nt=0;nt<2;nt++){
    b1v[nt] = b1[(2*w+nt)*16 + l16];
    b2v[nt] = b2[(2*w+nt)*16 + l16];
  }
  const s16x8 zvec = {0,0,0,0,0,0,0,0};

  // G1
  {
    f32x4 a1[4][2];
    #pragma unroll
    for(int mt=0;mt<4;mt++)
      #pragma unroll
      for(int nt=0;nt<2;nt++) a1[mt][nt] = (f32x4){0.f,0.f,0.f,0.f};
    s16x8 Af[4];
    #pragma unroll
    for(int mt=0;mt<4;mt++){
      s16x8 v = *(const s16x8*)&eipb[(R0 + mt*16 + l16)*16 + (quad&1)*8];
      if(quad >= 2) v = zvec;
      Af[mt] = v;
    }
    #pragma unroll
    for(int nt=0;nt<2;nt++){
      s16x8 Bf = *(const s16x8*)&W1T[((2*w+nt)*16 + l16)*32 + quad*8];
      #pragma unroll
      for(int mt=0;mt<4;mt++) a1[mt][nt] = mfma16(Af[mt], Bf, a1[mt][nt]);
    }
    #pragma unroll
    for(int mt=0;mt<4;mt++)
      #pragma unroll
      for(int nt=0;nt<2;nt++)
        #pragma unroll
        for(int i=0;i<4;i++)
          s_buf[(mt*16 + quad*4 + i)*T1S + (2*w+nt)*16 + l16] = f2bf(gelu_f(a1[mt][nt][i] + b1v[nt]));
  }
  __syncthreads();
  // G2
  f32x4 a2[4][2];
  #pragma unroll
  for(int mt=0;mt<4;mt++)
    #pragma unroll
    for(int nt=0;nt<2;nt++) a2[mt][nt] = (f32x4){0.f,0.f,0.f,0.f};
  #pragma unroll
  for(int ks=0; ks<4; ks++){
    s16x8 Af[4];
    #pragma unroll
    for(int mt=0;mt<4;mt++)
      Af[mt] = *(const s16x8*)&s_buf[(mt*16 + l16)*T1S + ks*32 + quad*8];
    #pragma unroll
    for(int nt=0;nt<2;nt++){
      s16x8 Bf = *(const s16x8*)&W2T[((2*w+nt)*16 + l16)*HD + ks*32 + quad*8];
      #pragma unroll
      for(int mt=0;mt<4;mt++) a2[mt][nt] = mfma16(Af[mt], Bf, a2[mt][nt]);
    }
  }
  __syncthreads();
  #pragma unroll
  for(int mt=0;mt<4;mt++)
    #pragma unroll
    for(int nt=0;nt<2;nt++)
      #pragma unroll
      for(int i=0;i<4;i++)
        s_buf[(mt*16 + quad*4 + i)*T1S + (2*w+nt)*16 + l16] = f2bf(gelu_f(a2[mt][nt][i] + b2v[nt]));
  __syncthreads();
  // G3 (simple per-layer loop)
  for(int l=0; l<nl; l++){
    f32x4 a3[4][2];
    #pragma unroll
    for(int mt=0;mt<4;mt++)
      #pragma unroll
      for(int nt=0;nt<2;nt++) a3[mt][nt] = (f32x4){0.f,0.f,0.f,0.f};
    #pragma unroll
    for(int ks=0; ks<4; ks++){
      s16x8 Af[4];
      #pragma unroll
      for(int mt=0;mt<4;mt++)
        Af[mt] = *(const s16x8*)&s_buf[(mt*16 + l16)*T1S + ks*32 + quad*8];
      #pragma unroll
      for(int nt=0;nt<2;nt++){
        s16x8 Bf = *(const s16x8*)&WCT[l*16384 + ((2*w+nt)*16 + l16)*HD + ks*32 + quad*8];
        #pragma unroll
        for(int mt=0;mt<4;mt++) a3[mt][nt] = mfma16(Af[mt], Bf, a3[mt][nt]);
      }
    }
    #pragma unroll
    for(int mt=0;mt<4;mt++)
      #pragma unroll
      for(int nt=0;nt<2;nt++)
        #pragma unroll
        for(int i=0;i<4;i++)
          kern[l*kstride + (R0 + mt*16 + quad*4 + i)*HD + (2*w+nt)*16 + l16] = f2bf(a3[mt][nt][i]);
  }
}

// ---------------- gather + fiber mix + LN -> bf16 h (fast path) ----------------
__global__ __launch_bounds__(256) void k_gather(
    const u16* __restrict__ kern, const float* __restrict__ x,
    const int* __restrict__ rowptr, const int* __restrict__ srcs,
    const float* __restrict__ fkl, const float* __restrict__ bconv,
    const float* __restrict__ gamma, const float* __restrict__ beta,
    u16* __restrict__ hout)
{
  int n = blockIdx.x, t = threadIdx.x;
  int c = t & 127, half = t >> 7;      // half 0: k=0..5, half 1: k=6..11
  int w = t >> 6, lane = t & 63;
  __shared__ float raw[NGRID*HD];      // 6 KB
  __shared__ float red[4][6], red2[4][6];
  int base = rowptr[n];
  int d = rowptr[n+1] - base;
  float acc[6] = {0.f,0.f,0.f,0.f,0.f,0.f};
  int srcn = (d > 0) ? srcs[base] : 0;
  for(int e=0; e<d; e++){
    int nsrc = (e+1 < d) ? srcs[base+e+1] : 0;   // prefetch next src
    const u16*   kp = &kern[((size_t)(base+e)*NGRID + half*6)*HD + c];
    const float* xp = &x[((size_t)srcn*NGRID + half*6)*HD + c];
    #pragma unroll
    for(int kk=0;kk<6;kk++)
      acc[kk] += bf2f(kp[kk*HD]) * xp[kk*HD];
    srcn = nsrc;
  }
  #pragma unroll
  for(int kk=0;kk<6;kk++)
    raw[(half*6+kk)*HD + c] = acc[kk];
  __syncthreads();
  float bc = bconv[c];
  float v[6];
  #pragma unroll
  for(int kk=0;kk<6;kk++){
    int p = half*6 + kk;
    float a = 0.f;
    #pragma unroll
    for(int o=0;o<NGRID;o++)
      a += raw[o*HD + c] * fkl[(p*NGRID+o)*HD + c];
    v[kk] = a * (1.0f/12.0f) + bc;
  }
  #pragma unroll
  for(int kk=0;kk<6;kk++){
    float s = waveReduceSum(v[kk]);
    if(lane == 0) red[w][kk] = s;
  }
  __syncthreads();
  float dd[6];
  #pragma unroll
  for(int kk=0;kk<6;kk++){
    float mu = (red[half*2][kk] + red[half*2+1][kk]) * (1.0f/128.0f);
    dd[kk] = v[kk] - mu;
    float s2 = waveReduceSum(dd[kk]*dd[kk]);
    if(lane == 0) red2[w][kk] = s2;
  }
  __syncthreads();
  float ga = gamma[c], be = beta[c];
  #pragma unroll
  for(int kk=0;kk<6;kk++){
    float var = (red2[half*2][kk] + red2[half*2+1][kk]) * (1.0f/128.0f);
    float inv = 1.0f / sqrtf(var + 1e-5f);
    hout[((size_t)n*NGRID + half*6 + kk)*HD + c] = f2bf(dd[kk] * inv * ga + be);
  }
}

// ---------------- FF1 as dense row-GEMM: h4 = gelu(h @ Wff1 + b1), 32 rows/block ----------------
__global__ __launch_bounds__(256) void k_ff1(
    const u16* __restrict__ F1T, const float* __restrict__ bf1,
    const u16* __restrict__ hin, u16* __restrict__ h4)
{
  int t = threadIdx.x;
  size_t r0 = (size_t)blockIdx.x * 32;
  int lane = t & 63, w = t >> 6, quad = lane >> 4, l16 = lane & 15;
  __shared__ __align__(16) u16 sxh[32*T1S];   // 8.7 KB
  for(int i=t; i<32*HD/8; i+=256){
    int r = (i*8) >> 7, cc = (i*8) & 127;
    *(s16x8*)&sxh[r*T1S + cc] = *(const s16x8*)&hin[r0*HD + (size_t)i*8];
  }
  __syncthreads();
  f32x4 acc[2][8];
  #pragma unroll
  for(int mt=0;mt<2;mt++)
    #pragma unroll
    for(int j=0;j<8;j++) acc[mt][j] = (f32x4){0.f,0.f,0.f,0.f};
  #pragma unroll
  for(int ks=0; ks<4; ks++){
    s16x8 Af0 = *(const s16x8*)&sxh[l16*T1S + ks*32 + quad*8];
    s16x8 Af1 = *(const s16x8*)&sxh[(16 + l16)*T1S + ks*32 + quad*8];
    #pragma unroll
    for(int j=0;j<8;j++){
      int nt = w*8 + j;
      s16x8 Bf = *(const s16x8*)&F1T[((size_t)(nt*16 + l16))*HD + ks*32 + quad*8];
      acc[0][j] = mfma16(Af0, Bf, acc[0][j]);
      acc[1][j] = mfma16(Af1, Bf, acc[1][j]);
    }
  }
  #pragma unroll
  for(int j=0;j<8;j++){
    int col = (w*8+j)*16 + l16;
    float bv = bf1[col];
    #pragma unroll
    for(int mt=0;mt<2;mt++)
      #pragma unroll
      for(int i=0;i<4;i++){
        int row = mt*16 + quad*4 + i;
        h4[(r0 + row)*H4 + col] = f2bf(gelu_f(acc[mt][j][i] + bv));
      }
  }
}

// ---------------- FF2 as dense row-GEMM + residual: x += h4 @ Wff2 + b2 ----------------
__global__ __launch_bounds__(256) void k_ff2(
    const u16* __restrict__ F2T, const float* __restrict__ bf2,
    const u16* __restrict__ h4, float* __restrict__ x)
{
  int t = threadIdx.x;
  size_t r0 = (size_t)blockIdx.x * 32;
  int lane = t & 63, w = t >> 6, quad = lane >> 4, l16 = lane & 15;
  f32x4 acc[2][2];
  #pragma unroll
  for(int mt=0;mt<2;mt++)
    #pragma unroll
    for(int j=0;j<2;j++) acc[mt][j] = (f32x4){0.f,0.f,0.f,0.f};
  for(int ks=0; ks<16; ks++){
    s16x8 Af0 = *(const s16x8*)&h4[(r0 + l16)*H4 + ks*32 + quad*8];
    s16x8 Af1 = *(const s16x8*)&h4[(r0 + 16 + l16)*H4 + ks*32 + quad*8];
    #pragma unroll
    for(int j=0;j<2;j++){
      int nt = w*2 + j;
      s16x8 Bf = *(const s16x8*)&F2T[((size_t)(nt*16 + l16))*H4 + ks*32 + quad*8];
      acc[0][j] = mfma16(Af0, Bf, acc[0][j]);
      acc[1][j] = mfma16(Af1, Bf, acc[1][j]);
    }
  }
  #pragma unroll
  for(int j=0;j<2;j++){
    int col = (w*2+j)*16 + l16;
    float bv = bf2[col];
    #pragma unroll
    for(int mt=0;mt<2;mt++)
      #pragma unroll
      for(int i=0;i<4;i++){
        size_t row = r0 + mt*16 + quad*4 + i;
        x[row*HD + col] += acc[mt][j][i] + bv;
      }
  }
}

// ---------------- SLOW fallback conv (round-5 structure, used if ws too small) ----------------
__global__ __launch_bounds__(256) void k_conv_slow(
    const u16* __restrict__ eipb, const u16* __restrict__ W1T,
    const float* __restrict__ b1, const float* __restrict__ b2,
    const u16* __restrict__ W2T, const u16* __restrict__ WCT,
    const float* __restrict__ x,
    const int* __restrict__ rowptr, const int* __restrict__ srcs,
    float* __restrict__ x1o)
{
  int n = blockIdx.x; int t = threadIdx.x;
  int lane = t & 63, w = t >> 6, quad = lane >> 4, l16 = lane & 15;

  __shared__ __align__(16) u16 s_t1h[48*T1S];
  __shared__ __align__(16) u16 s_bas[48*T1S];
  __shared__ __align__(16) float accLDS[NGRID*HD];

  int base = rowptr[n];
  int d = rowptr[n+1] - base;

  float b1v[2], b2v[2];
  #pragma unroll
  for(int nt=0;nt<2;nt++){
    b1v[nt] = b1[(2*w+nt)*16 + l16];
    b2v[nt] = b2[(2*w+nt)*16 + l16];
  }

  for(int i=t; i<NGRID*HD; i+=256) accLDS[i] = 0.f;
  __syncthreads();

  f32x4 accv[3][2];
  #pragma unroll
  for(int mt=0;mt<3;mt++)
    #pragma unroll
    for(int nt=0;nt<2;nt++) accv[mt][nt] = (f32x4){0.f,0.f,0.f,0.f};

  const s16x8 zvec = {0,0,0,0,0,0,0,0};

  for(int ch=0; ch<d; ch+=4){
    size_t rowb = (size_t)(base + ch) * NGRID;
    s16x8 Af1[3];
    #pragma unroll
    for(int mt=0;mt<3;mt++){
      s16x8 v = *(const s16x8*)&eipb[(rowb + mt*16 + l16)*16 + (quad&1)*8];
      if(quad >= 2) v = zvec;
      Af1[mt] = v;
    }
    float xv[3][4][2];
    #pragma unroll
    for(int mt=0;mt<3;mt++)
      #pragma unroll
      for(int i=0;i<4;i++){
        int row = mt*16 + quad*4 + i;
        int e = row / 12;
        int k = row - e*12;
        int ei2 = base + ch + e;
        int srcn = srcs[min(ei2, NEDGES-1)];
        float m = (ch + e < d) ? 1.0f : 0.0f;
        const float* xp = &x[((size_t)srcn*NGRID + k)*HD + l16];
        #pragma unroll
        for(int nt=0;nt<2;nt++)
          xv[mt][i][nt] = xp[(2*w+nt)*16] * m;
      }
    {
      f32x4 a1[3][2];
      #pragma unroll
      for(int mt=0;mt<3;mt++)
        #pragma unroll
        for(int nt=0;nt<2;nt++) a1[mt][nt] = (f32x4){0.f,0.f,0.f,0.f};
      #pragma unroll
      for(int nt=0;nt<2;nt++){
        s16x8 Bf = *(const s16x8*)&W1T[((2*w+nt)*16 + l16)*32 + quad*8];
        #pragma unroll
        for(int mt=0;mt<3;mt++) a1[mt][nt] = mfma16(Af1[mt], Bf, a1[mt][nt]);
      }
      #pragma unroll
      for(int mt=0;mt<3;mt++)
        #pragma unroll
        for(int nt=0;nt<2;nt++)
          #pragma unroll
          for(int i=0;i<4;i++)
            s_t1h[(mt*16 + quad*4 + i)*T1S + (2*w+nt)*16 + l16] = f2bf(gelu_f(a1[mt][nt][i] + b1v[nt]));
    }
    __syncthreads();
    {
      f32x4 a2[3][2];
      #pragma unroll
      for(int mt=0;mt<3;mt++)
        #pragma unroll
        for(int nt=0;nt<2;nt++) a2[mt][nt] = (f32x4){0.f,0.f,0.f,0.f};
      #pragma unroll
      for(int ks=0; ks<4; ks++){
        s16x8 Af[3];
        #pragma unroll
        for(int mt=0;mt<3;mt++)
          Af[mt] = *(const s16x8*)&s_t1h[(mt*16 + l16)*T1S + ks*32 + quad*8];
        #pragma unroll
        for(int nt=0;nt<2;nt++){
          s16x8 Bf = *(const s16x8*)&W2T[((2*w+nt)*16 + l16)*HD + ks*32 + quad*8];
          #pragma unroll
          for(int mt=0;mt<3;mt++) a2[mt][nt] = mfma16(Af[mt], Bf, a2[mt][nt]);
        }
      }
      #pragma unroll
      for(int mt=0;mt<3;mt++)
        #pragma unroll
        for(int nt=0;nt<2;nt++)
          #pragma unroll
          for(int i=0;i<4;i++)
            s_bas[(mt*16 + quad*4 + i)*T1S + (2*w+nt)*16 + l16] = f2bf(gelu_f(a2[mt][nt][i] + b2v[nt]));
    }
    __syncthreads();
    {
      f32x4 a3[3][2];
      #pragma unroll
      for(int mt=0;mt<3;mt++)
        #pragma unroll
        for(int nt=0;nt<2;nt++) a3[mt][nt] = (f32x4){0.f,0.f,0.f,0.f};
      #pragma unroll
      for(int ks=0; ks<4; ks++){
        s16x8 Af[3];
        #pragma unroll
        for(int mt=0;mt<3;mt++)
          Af[mt] = *(const s16x8*)&s_bas[(mt*16 + l16)*T1S + ks*32 + quad*8];
        #pragma unroll
        for(int nt=0;nt<2;nt++){
          s16x8 Bf = *(const s16x8*)&WCT[((2*w+nt)*16 + l16)*HD + ks*32 + quad*8];
          #pragma unroll
          for(int mt=0;mt<3;mt++) a3[mt][nt] = mfma16(Af[mt], Bf, a3[mt][nt]);
        }
      }
      #pragma unroll
      for(int mt=0;mt<3;mt++)
        #pragma unroll
        for(int nt=0;nt<2;nt++)
          #pragma unroll
          for(int i=0;i<4;i++)
            accv[mt][nt][i] += a3[mt][nt][i] * xv[mt][i][nt];
    }
  }
  __syncthreads();
  #pragma unroll
  for(int mt=0;mt<3;mt++)
    #pragma unroll
    for(int nt=0;nt<2;nt++)
      #pragma unroll
      for(int i=0;i<4;i++){
        int row = mt*16 + quad*4 + i;
        int k = row % 12;
        atomicAdd(&accLDS[k*HD + (2*w+nt)*16 + l16], accv[mt][nt][i]);
      }
  __syncthreads();
  for(int i=t; i<NGRID*HD; i+=256)
    x1o[(size_t)n*NGRID*HD + i] = accLDS[i];
}

// ---------------- slow-path fused mix + LN + FF + residual (per node) ----------------
constexpr int STS = 520;
__global__ __launch_bounds__(256) void k_ffln(
    const u16* __restrict__ F1T, const float* __restrict__ bf1,
    const u16* __restrict__ F2T, const float* __restrict__ bf2,
    const float* __restrict__ x1raw,
    const float* __restrict__ fkl, const float* __restrict__ bconv,
    const float* __restrict__ gamma, const float* __restrict__ beta,
    float* __restrict__ x)
{
  int n = blockIdx.x; int t = threadIdx.x;
  int lane = t & 63, w = t >> 6, quad = lane >> 4, l16 = lane & 15;
  __shared__ __align__(16) float raw[NGRID*HD];
  __shared__ __align__(16) u16 sxh[16*T1S];
  __shared__ __align__(16) u16 st[16*STS];

  for(int i=t; i<NGRID*HD; i+=256) raw[i] = x1raw[(size_t)n*NGRID*HD + i];
  for(int i=t; i<4*T1S; i+=256) sxh[12*T1S + i] = 0;
  __syncthreads();

  {
    int c0 = lane, c1 = lane + 64;
    float bc0 = bconv[c0], bc1 = bconv[c1];
    float ga0 = gamma[c0], ga1 = gamma[c1];
    float be0 = beta[c0],  be1 = beta[c1];
    #pragma unroll
    for(int pp=0; pp<3; pp++){
      int p = w + pp*4;
      float a0 = 0.f, a1 = 0.f;
      #pragma unroll
      for(int o=0;o<NGRID;o++){
        a0 += raw[o*HD + c0] * fkl[(p*NGRID+o)*HD + c0];
        a1 += raw[o*HD + c1] * fkl[(p*NGRID+o)*HD + c1];
      }
      float v0 = a0 * (1.0f/12.0f) + bc0;
      float v1 = a1 * (1.0f/12.0f) + bc1;
      float mu = waveReduceSum(v0 + v1) * (1.0f/128.0f);
      float d0 = v0 - mu, d1 = v1 - mu;
      float var = waveReduceSum(d0*d0 + d1*d1) * (1.0f/128.0f);
      float inv = 1.0f / sqrtf(var + 1e-5f);
      sxh[p*T1S + c0] = f2bf(d0 * inv * ga0 + be0);
      sxh[p*T1S + c1] = f2bf(d1 * inv * ga1 + be1);
    }
  }
  __syncthreads();
  {
    f32x4 acc1[8];
    #pragma unroll
    for(int j=0;j<8;j++) acc1[j] = (f32x4){0.f,0.f,0.f,0.f};
    #pragma unroll
    for(int ks=0; ks<4; ks++){
      s16x8 Af = *(const s16x8*)&sxh[l16*T1S + ks*32 + quad*8];
      #pragma unroll
      for(int j=0;j<8;j++){
        int nt = w*8 + j;
        s16x8 Bf = *(const s16x8*)&F1T[((size_t)(nt*16 + l16))*HD + ks*32 + quad*8];
        acc1[j] = mfma16(Af, Bf, acc1[j]);
      }
    }
    #pragma unroll
    for(int j=0;j<8;j++){
      int col = (w*8+j)*16 + l16;
      float bv = bf1[col];
      #pragma unroll
      for(int i=0;i<4;i++){
        int row = quad*4 + i;
        st[row*STS + col] = f2bf(gelu_f(acc1[j][i] + bv));
      }
    }
  }
  __syncthreads();
  {
    f32x4 acc2[2];
    #pragma unroll
    for(int j=0;j<2;j++) acc2[j] = (f32x4){0.f,0.f,0.f,0.f};
    for(int ks=0; ks<16; ks++){
      s16x8 Af = *(const s16x8*)&st[l16*STS + ks*32 + quad*8];
      #pragma unroll
      for(int j=0;j<2;j++){
        int nt = w*2 + j;
        s16x8 Bf = *(const s16x8*)&F2T[((size_t)(nt*16 + l16))*H4 + ks*32 + quad*8];
        acc2[j] = mfma16(Af, Bf, acc2[j]);
      }
    }
    #pragma unroll
    for(int j=0;j<2;j++){
      int col = (w*2+j)*16 + l16;
      float bv = bf2[col];
      #pragma unroll
      for(int i=0;i<4;i++){
        int row = quad*4 + i;
        if(row < NGRID){
          size_t idx = ((size_t)n*NGRID + row)*HD + col;
          x[idx] += acc2[j][i] + bv;
        }
      }
    }
  }
}

// ---------------- readout (MFMA, 2 nodes/block) ----------------
__global__ __launch_bounds__(256) void k_readout(
    const float* __restrict__ x, const float* __restrict__ grid_node,
    const u16* __restrict__ RO1T, const float* __restrict__ br1,
    const float* __restrict__ Wr2, const float* __restrict__ br2,
    float* __restrict__ out)
{
  int t = threadIdx.x;
  int n0 = blockIdx.x * 2;
  int lane = t & 63, w = t >> 6, quad = lane >> 4, l16 = lane & 15;
  __shared__ __align__(16) u16 sxh[32*T1S];
  __shared__ float sy[32];
  if(t < 32) sy[t] = 0.f;
  for(int i=t; i<2*NGRID*HD; i+=256){
    int nd = i / (NGRID*HD), rem = i - nd*NGRID*HD;
    int r = rem >> 7, c = rem & 127;
    sxh[(nd*16 + r)*T1S + c] = f2bf(x[(size_t)n0*NGRID*HD + i]);
  }
  for(int i=t; i<4*T1S; i+=256){ sxh[12*T1S + i] = 0; sxh[28*T1S + i] = 0; }
  __syncthreads();
  f32x4 acc[2][2];
  #pragma unroll
  for(int mt=0;mt<2;mt++)
    #pragma unroll
    for(int j=0;j<2;j++) acc[mt][j] = (f32x4){0.f,0.f,0.f,0.f};
  #pragma unroll
  for(int ks=0; ks<4; ks++){
    s16x8 Af0 = *(const s16x8*)&sxh[l16*T1S + ks*32 + quad*8];
    s16x8 Af1 = *(const s16x8*)&sxh[(16 + l16)*T1S + ks*32 + quad*8];
    #pragma unroll
    for(int j=0;j<2;j++){
      int nt = w*2 + j;
      s16x8 Bf = *(const s16x8*)&RO1T[((size_t)(nt*16 + l16))*HD + ks*32 + quad*8];
      acc[0][j] = mfma16(Af0, Bf, acc[0][j]);
      acc[1][j] = mfma16(Af1, Bf, acc[1][j]);
    }
  }
  #pragma unroll
  for(int j=0;j<2;j++){
    int col = (w*2+j)*16 + l16;
    float bv = br1[col];
    float w2v = Wr2[col];
    #pragma unroll
    for(int mt=0;mt<2;mt++)
      #pragma unroll
      for(int i=0;i<4;i++){
        int row = quad*4 + i;
        if(row < NGRID)
          atomicAdd(&sy[mt*16 + row], gelu_f(acc[mt][j][i] + bv) * w2v);
      }
  }
  __syncthreads();
  if(t < 6){
    int nd = t / 3, d = t - nd*3;
    float b2v = br2[0];
    float s = 0.f;
    #pragma unroll
    for(int k=0;k<NGRID;k++)
      s += grid_node[((size_t)(n0+nd)*NGRID + k)*3 + d] * (sy[nd*16 + k] + b2v);
    out[(n0+nd)*3 + d] = s * (1.0f/12.0f);
  }
}

extern "C" void kernel_launch(void* const* d_in, const int* in_sizes, int n_in,
                              void* d_out, int out_size, void* d_ws, size_t ws_size,
                              hipStream_t stream)
{
  const float* pos      = (const float*)d_in[0];
  const float* vel      = (const float*)d_in[1];
  const float* charges  = (const float*)d_in[2];
  const int*   batch    = (const int*)d_in[3];
  const int*   eidx     = (const int*)d_in[4];
  const float* grid0    = (const float*)d_in[5];
  const float* R        = (const float*)d_in[6];
  const float* W_b1     = (const float*)d_in[7];
  const float* b_b1     = (const float*)d_in[8];
  const float* W_b2     = (const float*)d_in[9];
  const float* b_b2     = (const float*)d_in[10];
  const float* W_fb1    = (const float*)d_in[11];
  const float* b_fb1    = (const float*)d_in[12];
  const float* W_fb2    = (const float*)d_in[13];
  const float* b_fb2    = (const float*)d_in[14];
  const float* W_embed  = (const float*)d_in[15];
  const float* W_conv   = (const float*)d_in[16];
  const float* W_fiber  = (const float*)d_in[17];
  const float* b_conv   = (const float*)d_in[18];
  const float* ln_g     = (const float*)d_in[19];
  const float* ln_b     = (const float*)d_in[20];
  const float* W_ff1    = (const float*)d_in[21];
  const float* b_ff1    = (const float*)d_in[22];
  const float* W_ff2    = (const float*)d_in[23];
  const float* b_ff2    = (const float*)d_in[24];
  const float* W_ro1    = (const float*)d_in[25];
  const float* b_ro1    = (const float*)d_in[26];
  const float* W_ro2    = (const float*)d_in[27];
  const float* b_ro2    = (const float*)d_in[28];

  float* ws        = (float*)d_ws;
  float* grid_node = ws + OFF_GN;
  float* possum    = ws + OFF_PS;
  float* pcnt      = ws + OFF_CNT;
  float* fk        = ws + OFF_FK;
  float* x         = ws + OFF_X;
  float* x1        = ws + OFF_X1;
  u16*   WB        = (u16*)(ws + OFF_WB);
  u16*   W2T       = WB + WB_W2T;
  u16*   WCT       = WB + WB_WCT;
  u16*   F1T       = WB + WB_F1T;
  u16*   F2T       = WB + WB_F2T;
  int*   rowptr    = (int*)(ws + OFF_ROWP);
  int*   deg       = (int*)(ws + OFF_DEG);
  int*   cur       = (int*)(ws + OFF_CUR);
  int*   esorted   = (int*)(ws + OFF_ESRT);
  u16*   eipb      = (u16*)(ws + OFF_EIPB);
  u16*   W1T       = (u16*)(ws + OFF_W1T);
  int*   srcs      = (int*)(ws + OFF_SRCS);
  u16*   kern1     = (u16*)(ws + OFF_BAS);
  u16*   RO1T      = (u16*)(ws + OFF_ESRT);   // reuses esorted after k_einv
  u16*   hbuf      = (u16*)x1;                // fast path: bf16 h buffer in x1 region
  const size_t KSTR = (size_t)600000 * HD;

  const bool fast = (ws_size >= OFF_END_FAST * sizeof(float));
  const bool dual = (ws_size >= OFF_END_DUAL * sizeof(float));

  hipMemsetAsync(possum, 0, 512*sizeof(float), stream);
  hipMemsetAsync(deg, 0, NNODES*sizeof(int), stream);
  hipMemsetAsync(cur, 0, NNODES*sizeof(int), stream);
  hipMemsetAsync(eipb + (size_t)NEDGES*NGRID*16, 0, 48*16*sizeof(u16), stream);

  k_stats<<<(NNODES+255)/256, 256, 0, stream>>>(pos, batch, possum, pcnt);
  k_gridnode<<<(NNODES*NGRID+255)/256, 256, 0, stream>>>(grid0, R, batch, grid_node);
  k_embed<<<NNODES, 128, 0, stream>>>(pos, vel, charges, batch, possum, pcnt, grid_node, W_embed, x);
  k_fiber<<<144, 128, 0, stream>>>(grid0, W_fb1, b_fb1, W_fb2, b_fb2, W_fiber, fk);

  k_prep<<<(315392+255)/256, 256, 0, stream>>>(W_b2, W_b1, W_conv, W_ff1, W_ff2,
                                               W2T, W1T, WCT, F1T, F2T);

  k_deg<<<(NEDGES+255)/256, 256, 0, stream>>>(eidx, deg);
  k_scan<<<1, 256, 0, stream>>>(deg, rowptr);
  k_bucket<<<(NEDGES+255)/256, 256, 0, stream>>>(eidx, rowptr, cur, esorted, srcs);

  k_einv<<<(NEDGES*NGRID+255)/256, 256, 0, stream>>>(esorted, eidx, pos, charges, grid_node, eipb);
  // esorted now dead -> RO1T prep into its region
  k_prepro<<<64, 256, 0, stream>>>(W_ro1, RO1T);

  if(fast){
    if(dual)
      k_kern<<<9375, 256, 0, stream>>>(eipb, W1T, b_b1, b_b2, W2T, WCT, kern1, 2, KSTR);
    for(int l=0; l<NLAY; l++){
      if(!dual)
        k_kern<<<9375, 256, 0, stream>>>(eipb, W1T, b_b1, b_b2, W2T, WCT + (size_t)l*16384,
                                         kern1, 1, 0);
      const u16* kl = dual ? (kern1 + (size_t)l*KSTR) : kern1;
      // h4 scratch aliases the CURRENT layer's kern buffer (dead after its gather)
      u16* h4 = dual ? (kern1 + (size_t)l*KSTR) : kern1;
      k_gather<<<NNODES, 256, 0, stream>>>(kl, x, rowptr, srcs,
          fk + (size_t)l*144*HD, b_conv + l*HD, ln_g + l*HD, ln_b + l*HD, hbuf);
      k_ff1<<<NNODES*NGRID/32, 256, 0, stream>>>(F1T + (size_t)l*65536, b_ff1 + l*H4, hbuf, h4);
      k_ff2<<<NNODES*NGRID/32, 256, 0, stream>>>(F2T + (size_t)l*65536, b_ff2 + l*HD, h4, x);
    }
  } else {
    for(int l=0; l<NLAY; l++){
      k_conv_slow<<<NNODES, 256, 0, stream>>>(eipb, W1T, b_b1, b_b2, W2T, WCT + (size_t)l*16384,
          x, rowptr, srcs, x1);
      k_ffln<<<NNODES, 256, 0, stream>>>(F1T + (size_t)l*65536, b_ff1 + l*H4,
          F2T + (size_t)l*65536, b_ff2 + l*HD, x1,
          fk + (size_t)l*144*HD, b_conv + l*HD, ln_g + l*HD, ln_b + l*HD, x);
    }
  }

  k_readout<<<NNODES/2, 256, 0, stream>>>(x, grid_node, RO1T, b_ro1, W_ro2, b_ro2, (float*)d_out);
}